// Round 6
// baseline (149.379 us; speedup 1.0000x reference)
//
#include <hip/hip_runtime.h>

#define BATCH 32
#define I_TOT 4096
#define N_CAP 16
#define K_DIM 128
#define RCHUNK 128
#define NCHUNK 32          // routing chunks (128 rows each)
#define CCHUNK 64          // pack/colsum chunk rows
#define NCHUNK_CS 64       // colsum partial count

// float-offsets in ws
#define WS_WO   0                      // [B][2048] f32
#define WS_SP   65536                  // [B][32][2048] f32 (colsum partials [B][64][128] alias; consumed before routing writes)
#define WS_PACK 2162688                // packed bf16: 16,777,216 ushorts (8M float-slots)
#define WS_TOTAL_F (WS_PACK + 8388608)

typedef __attribute__((ext_vector_type(8))) short bf16x8;
typedef __attribute__((ext_vector_type(4))) float f32x4;

__device__ inline ushort f2bf(float x) {
    unsigned u = __float_as_uint(x);
    u += 0x7FFFu + ((u >> 16) & 1u);   // round-to-nearest-even
    return (ushort)(u >> 16);
}
__device__ inline float bf2f(ushort x) {
    return __uint_as_float(((unsigned)x) << 16);
}

// ---------------------------------------------------------------------------
// K0: pack u -> bf16 A-fragment tiles + colsum partials. grid (64, B), block 256.
// Packed layout: idx = (((b*256 + (row>>4))*4 + (k>>5))*64 + (row&15) + 16*((k&31)>>3))*8 + (k&7)
__global__ __launch_bounds__(256) void pack_kernel(const float* __restrict__ u,
                                                   float* __restrict__ ws, int do_pack) {
    const int b = blockIdx.y, chunk = blockIdx.x, t = threadIdx.x;
    const int c0 = chunk * CCHUNK;
    ushort* up = (ushort*)(ws + WS_PACK);
    const int k4 = t & 31, rg = t >> 5;
    float4 acc = {0.f, 0.f, 0.f, 0.f};
    #pragma unroll
    for (int m = 0; m < 8; m++) {
        int R = c0 + m * 8 + rg;
        float4 v = *(const float4*)&u[((size_t)b * I_TOT + R) * K_DIM + k4 * 4];
        acc.x += v.x; acc.y += v.y; acc.z += v.z; acc.w += v.w;
        if (do_pack) {
            int k = k4 * 4;
            int kt = k >> 5, lane_hi = (k & 31) >> 3, j0 = k & 7;
            size_t off = (((size_t)(b * 256 + (R >> 4)) * 4 + kt) * 64
                          + (R & 15) + (lane_hi << 4)) * 8 + j0;
            ushort4 w = { f2bf(v.x), f2bf(v.y), f2bf(v.z), f2bf(v.w) };
            *(ushort4*)&up[off] = w;
        }
    }
    __shared__ __align__(16) float4 red[8][32];
    red[rg][k4] = acc;
    __syncthreads();
    if (t < 32) {
        float4 s = red[0][t];
        #pragma unroll
        for (int r = 1; r < 8; r++) {
            float4 v = red[r][t];
            s.x += v.x; s.y += v.y; s.z += v.z; s.w += v.w;
        }
        *(float4*)&ws[WS_SP + ((size_t)(b * NCHUNK_CS + chunk)) * K_DIM + t * 4] = s;
    }
}

// ---------------------------------------------------------------------------
// K2: per-(capsule,batch) update. grid (N_CAP, BATCH), block 128.
__global__ __launch_bounds__(128) void update_kernel(const float* __restrict__ W,
                                                     float* __restrict__ ws,
                                                     float* __restrict__ out,
                                                     int mode) {
    const int n = blockIdx.x, b = blockIdx.y, t = threadIdx.x;

    __shared__ float s_n[K_DIM];
    __shared__ float o_s[N_CAP + 4];

    if (mode == 0) {
        const float* sp = ws + WS_SP + (size_t)b * NCHUNK_CS * K_DIM;
        float a = 0.f;
        #pragma unroll 8
        for (int c = 0; c < NCHUNK_CS; c++) a += sp[(size_t)c * K_DIM + t];
        s_n[t] = a * (1.f / 16.f);
    } else {
        const float* sp = ws + WS_SP + (size_t)b * NCHUNK * 2048 + n * K_DIM;
        float a = 0.f;
        #pragma unroll 8
        for (int c = 0; c < NCHUNK; c++) a += sp[(size_t)c * 2048 + t];
        s_n[t] = a;
    }
    __syncthreads();

    {
        const int d = t >> 3, kseg = t & 7;
        const int col = n * 16 + d;
        float p = 0.f;
        #pragma unroll
        for (int j = 0; j < 16; j++) {
            int k = kseg * 16 + j;
            p += s_n[k] * W[k * 256 + col];
        }
        p += __shfl_xor(p, 1); p += __shfl_xor(p, 2); p += __shfl_xor(p, 4);
        if (kseg == 0) o_s[d] = p;
    }
    __syncthreads();

    float ss = (mode == 2) ? 1e-7f : 0.f;
    #pragma unroll
    for (int d = 0; d < 16; d++) { float v = o_s[d]; ss += v * v; }

    if (mode == 2) {
        if (t < 16) {
            float scale = sqrtf(ss) / (0.5f + ss);
            out[b * 256 + n * 16 + t] = scale * o_s[t];
        }
        return;
    }

    const float inv = rsqrtf(fmaxf(ss, 1e-12f));
    const float4* wrow = (const float4*)(W + t * 256 + n * 16);
    const float4* o4 = (const float4*)o_s;
    float acc = 0.f;
    #pragma unroll
    for (int q = 0; q < 4; q++) {
        float4 w = wrow[q];
        float4 o = o4[q];
        acc += w.x * o.x + w.y * o.y + w.z * o.z + w.w * o.w;
    }
    ws[WS_WO + (size_t)b * 2048 + n * K_DIM + t] = acc * inv;
}

// ---------------------------------------------------------------------------
// K3a: MFMA routing pass. grid (32, B), block 256 (4 waves, 2 row-tiles each).
// Phase 2 now reads the SAME packed bf16 tile (L2-hot) instead of fp32 u.
__global__ __launch_bounds__(256) void routing_mfma(float* __restrict__ ws) {
    const int b = blockIdx.y, chunk = blockIdx.x, t = threadIdx.x;
    const int lane = t & 63, wave = t >> 6;
    const short* up = (const short*)(ws + WS_PACK);

    __shared__ __align__(16) short wo_bf[N_CAP][144];
    __shared__ float c_s[RCHUNK][N_CAP];

    const float* wo = ws + WS_WO + (size_t)b * 2048;
    #pragma unroll
    for (int j = 0; j < 8; j++) {
        int idx = t + j * 256;
        wo_bf[idx >> 7][idx & 127] = (short)f2bf(wo[idx]);
    }
    __syncthreads();

    const int cap = lane & 15, hi = lane >> 4;
    bf16x8 bfrag[4];
    #pragma unroll
    for (int kt = 0; kt < 4; kt++)
        bfrag[kt] = *(const bf16x8*)&wo_bf[cap][kt * 32 + hi * 8];

    #pragma unroll
    for (int rr = 0; rr < 2; rr++) {
        const int rt = wave * 2 + rr;
        const int rt_g = chunk * 8 + rt;
        f32x4 acc = {0.f, 0.f, 0.f, 0.f};
        const short* abase = up + (((size_t)(b * 256 + rt_g)) * 4) * 512 + lane * 8;
        #pragma unroll
        for (int kt = 0; kt < 4; kt++) {
            bf16x8 a = *(const bf16x8*)(abase + kt * 512);
            acc = __builtin_amdgcn_mfma_f32_16x16x32_bf16(a, bfrag[kt], acc, 0, 0, 0);
        }
        // softmax over caps: D layout col=lane&15 (cap), row=(lane>>4)*4+reg
        #pragma unroll
        for (int r = 0; r < 4; r++) {
            float v = acc[r];
            float mx = v;
            mx = fmaxf(mx, __shfl_xor(mx, 1)); mx = fmaxf(mx, __shfl_xor(mx, 2));
            mx = fmaxf(mx, __shfl_xor(mx, 4)); mx = fmaxf(mx, __shfl_xor(mx, 8));
            float e = __expf(v - mx);
            float sm = e;
            sm += __shfl_xor(sm, 1); sm += __shfl_xor(sm, 2);
            sm += __shfl_xor(sm, 4); sm += __shfl_xor(sm, 8);
            c_s[rt * 16 + hi * 4 + r][cap] = e / sm;
        }
    }
    __syncthreads();

    // phase 2: k-parallel accumulation from packed bf16 (c fp32, acc fp32)
    const int k4 = t & 31, ng = t >> 5;
    const int k0 = k4 * 4;
    const int kt2 = k0 >> 5, khi2 = (k0 & 31) >> 3, j02 = k0 & 7;
    float4 a0 = {0.f,0.f,0.f,0.f}, a1 = {0.f,0.f,0.f,0.f};
    #pragma unroll
    for (int rl = 0; rl < 8; rl++) {
        const short* tb = up + (((size_t)(b * 256 + chunk * 8 + rl)) * 4 + kt2) * 512
                        + (khi2 << 4) * 8 + j02;
        #pragma unroll
        for (int il = 0; il < 16; il++) {
            ushort4 uv = *(const ushort4*)(tb + il * 8);
            float ux = bf2f(uv.x), uy = bf2f(uv.y), uz = bf2f(uv.z), uw = bf2f(uv.w);
            float2 c2 = *(const float2*)&c_s[rl * 16 + il][ng * 2];
            a0.x += ux * c2.x; a0.y += uy * c2.x; a0.z += uz * c2.x; a0.w += uw * c2.x;
            a1.x += ux * c2.y; a1.y += uy * c2.y; a1.z += uz * c2.y; a1.w += uw * c2.y;
        }
    }
    float* sp = ws + WS_SP + ((size_t)b * NCHUNK + chunk) * 2048;
    *(float4*)&sp[(ng * 2 + 0) * K_DIM + k0] = a0;
    *(float4*)&sp[(ng * 2 + 1) * K_DIM + k0] = a1;
}

// ---------------------------------------------------------------------------
// K3b: fp32 fallback routing if ws too small for the packed buffer.
__global__ __launch_bounds__(256) void routing_fp32(const float* __restrict__ u,
                                                    float* __restrict__ ws) {
    const int b = blockIdx.y, chunk = blockIdx.x, t = threadIdx.x;
    const int i0 = chunk * RCHUNK;

    __shared__ __align__(16) float wo_s[N_CAP][K_DIM];
    __shared__ __align__(16) float c_s[RCHUNK][N_CAP];

    const float* w_o = ws + WS_WO + (size_t)b * 2048;
    #pragma unroll
    for (int j = 0; j < 8; j++) {
        int idx = t + j * 256;
        ((float*)wo_s)[idx] = w_o[idx];
    }
    __syncthreads();

    {
        const int row = t >> 1, h = t & 1;
        const float4* upx = (const float4*)(u + ((size_t)b * I_TOT + i0 + row) * K_DIM + h * 64);
        const float4* wp = (const float4*)&wo_s[0][h * 64];
        float logit[16];
        #pragma unroll
        for (int n = 0; n < 16; n++) logit[n] = 0.f;
        #pragma unroll
        for (int q = 0; q < 16; q++) {
            float4 v = upx[q];
            #pragma unroll
            for (int n = 0; n < 16; n++) {
                float4 w = wp[n * 32 + q];
                logit[n] += v.x * w.x + v.y * w.y + v.z * w.z + v.w * w.w;
            }
        }
        #pragma unroll
        for (int n = 0; n < 16; n++) logit[n] += __shfl_xor(logit[n], 1);
        float m = logit[0];
        #pragma unroll
        for (int n = 1; n < 16; n++) m = fmaxf(m, logit[n]);
        float sum = 0.f;
        #pragma unroll
        for (int n = 0; n < 16; n++) { logit[n] = __expf(logit[n] - m); sum += logit[n]; }
        float inv = 1.f / sum;
        float4* crow = (float4*)&c_s[row][h * 8];
        if (h == 0) {
            crow[0] = make_float4(logit[0]*inv, logit[1]*inv, logit[2]*inv, logit[3]*inv);
            crow[1] = make_float4(logit[4]*inv, logit[5]*inv, logit[6]*inv, logit[7]*inv);
        } else {
            crow[0] = make_float4(logit[8]*inv, logit[9]*inv, logit[10]*inv, logit[11]*inv);
            crow[1] = make_float4(logit[12]*inv, logit[13]*inv, logit[14]*inv, logit[15]*inv);
        }
    }
    __syncthreads();

    const int k4 = t & 31, ng = t >> 5;
    float4 a0 = {0.f,0.f,0.f,0.f}, a1 = {0.f,0.f,0.f,0.f};
    const float4* u2 = (const float4*)(u + ((size_t)b * I_TOT + i0) * K_DIM) + k4;
    #pragma unroll 8
    for (int i = 0; i < RCHUNK; i++) {
        float4 v = u2[(size_t)i * 32];
        float2 c2 = *(const float2*)&c_s[i][ng * 2];
        a0.x += v.x * c2.x; a0.y += v.y * c2.x; a0.z += v.z * c2.x; a0.w += v.w * c2.x;
        a1.x += v.x * c2.y; a1.y += v.y * c2.y; a1.z += v.z * c2.y; a1.w += v.w * c2.y;
    }
    float* sp = ws + WS_SP + ((size_t)b * NCHUNK + chunk) * 2048;
    *(float4*)&sp[(ng * 2 + 0) * K_DIM + k4 * 4] = a0;
    *(float4*)&sp[(ng * 2 + 1) * K_DIM + k4 * 4] = a1;
}

// ---------------------------------------------------------------------------
extern "C" void kernel_launch(void* const* d_in, const int* in_sizes, int n_in,
                              void* d_out, int out_size, void* d_ws, size_t ws_size,
                              hipStream_t stream) {
    const float* u = (const float*)d_in[0];   // (32, 4096, 128) f32
    const float* W = (const float*)d_in[1];   // (128, 256) f32
    float* out = (float*)d_out;               // (32, 16, 16) f32
    float* ws = (float*)d_ws;

    const int big = (ws_size >= (size_t)WS_TOTAL_F * 4) ? 1 : 0;

    pack_kernel<<<dim3(I_TOT / CCHUNK, BATCH), 256, 0, stream>>>(u, ws, big);
    update_kernel<<<dim3(N_CAP, BATCH), 128, 0, stream>>>(W, ws, out, 0);

    for (int pass = 0; pass < 3; pass++) {
        if (big) routing_mfma<<<dim3(NCHUNK, BATCH), 256, 0, stream>>>(ws);
        else     routing_fp32<<<dim3(NCHUNK, BATCH), 256, 0, stream>>>(u, ws);
        update_kernel<<<dim3(N_CAP, BATCH), 128, 0, stream>>>(W, ws, out, pass == 2 ? 2 : 1);
    }
}

// Round 7
// 84.045 us; speedup vs baseline: 1.7774x; 1.7774x over previous
//
#include <hip/hip_runtime.h>

#define BATCH 32
#define I_TOT 4096
#define N_CAP 16
#define K_DIM 128
#define RCHUNK 128
#define NCHUNK 32          // routing chunks (128 rows each)
#define CCHUNK 64          // pack/colsum chunk rows
#define NCHUNK_CS 64       // colsum partial count

// float-offsets in ws
#define WS_WO    0                         // [B][2048] f32
#define WS_SP    65536                     // [B][32][2048] f32 (colsum partials alias; consumed before routing writes)
#define WS_PACK  2162688                   // row-major bf16 A-frags: 16,777,216 shorts (8M float-slots)
#define WS_PACKT (WS_PACK + 8388608)       // k-major bf16 A-frags (u^T): 16,777,216 shorts
#define WS_TOTAL_F (WS_PACKT + 8388608)

typedef __attribute__((ext_vector_type(8))) short bf16x8;
typedef __attribute__((ext_vector_type(4))) float f32x4;

__device__ inline ushort f2bf(float x) {
    unsigned u = __float_as_uint(x);
    u += 0x7FFFu + ((u >> 16) & 1u);   // round-to-nearest-even
    return (ushort)(u >> 16);
}

// ---------------------------------------------------------------------------
// K0: pack u -> (a) row-major bf16 A-frags [b][rowtile][kt][lane][8]
//              (b) k-major bf16 A-frags u_t [b][ktile(8)][ichunk(128)][lane][8]
//              (c) colsum partials. grid (64, B), block 256.
// Row-major frag:  lane=(row&15)+16*((k&31)>>3), j=k&7, tiles [row>>4][k>>5]
// K-major frag:    lane=(k&15)+16*((i&31)>>3),  j=i&7, tiles [k>>4][i>>5]
__global__ __launch_bounds__(256) void pack_kernel(const float* __restrict__ u,
                                                   float* __restrict__ ws, int do_pack) {
    const int b = blockIdx.y, chunk = blockIdx.x, t = threadIdx.x;
    const int c0 = chunk * CCHUNK;
    ushort* up = (ushort*)(ws + WS_PACK);
    ushort* ut = (ushort*)(ws + WS_PACKT);
    const int k4 = t & 31, rg = t >> 5;

    __shared__ ushort lds_bf[CCHUNK][K_DIM + 8];     // 64 x 136 bf16 (17.4 KB)
    __shared__ __align__(16) float4 red[8][32];

    float4 acc = {0.f, 0.f, 0.f, 0.f};
    #pragma unroll
    for (int m = 0; m < 8; m++) {
        int R = c0 + m * 8 + rg;
        float4 v = *(const float4*)&u[((size_t)b * I_TOT + R) * K_DIM + k4 * 4];
        acc.x += v.x; acc.y += v.y; acc.z += v.z; acc.w += v.w;
        if (do_pack) {
            ushort4 w = { f2bf(v.x), f2bf(v.y), f2bf(v.z), f2bf(v.w) };
            int k = k4 * 4;
            int kt = k >> 5, lane_hi = (k & 31) >> 3, j0 = k & 7;
            size_t off = (((size_t)(b * 256 + (R >> 4)) * 4 + kt) * 64
                          + (R & 15) + (lane_hi << 4)) * 8 + j0;
            *(ushort4*)&up[off] = w;
            *(ushort4*)&lds_bf[m * 8 + rg][k] = w;
        }
    }
    red[rg][k4] = acc;
    __syncthreads();
    if (t < 32) {
        float4 s = red[0][t];
        #pragma unroll
        for (int r = 1; r < 8; r++) {
            float4 v = red[r][t];
            s.x += v.x; s.y += v.y; s.z += v.z; s.w += v.w;
        }
        *(float4*)&ws[WS_SP + ((size_t)(b * NCHUNK_CS + chunk)) * K_DIM + t * 4] = s;
    }

    if (do_pack) {
        __syncthreads();   // lds_bf complete (uniform branch)
        // u_t: 1024 16B-chunks; chunk cc -> k = cc&127, i-octet io = cc>>7
        #pragma unroll
        for (int q = 0; q < 4; q++) {
            int cc = q * 256 + t;
            int k = cc & 127, io = cc >> 7;          // io 0..7
            int ig0 = c0 + io * 8;                   // global i base (octet)
            bf16x8 w8;
            #pragma unroll
            for (int j = 0; j < 8; j++) w8[j] = (short)lds_bf[io * 8 + j][k];
            size_t off = ((((size_t)(b * 8 + (k >> 4))) * 128 + (ig0 >> 5)) * 64
                          + (k & 15) + ((io & 3) << 4)) * 8;
            *(bf16x8*)&ut[off] = w8;
        }
    }
}

// ---------------------------------------------------------------------------
// K2: per-(capsule,batch) update. grid (N_CAP, BATCH), block 128.
__global__ __launch_bounds__(128) void update_kernel(const float* __restrict__ W,
                                                     float* __restrict__ ws,
                                                     float* __restrict__ out,
                                                     int mode) {
    const int n = blockIdx.x, b = blockIdx.y, t = threadIdx.x;

    __shared__ float s_n[K_DIM];
    __shared__ float o_s[N_CAP + 4];

    if (mode == 0) {
        const float* sp = ws + WS_SP + (size_t)b * NCHUNK_CS * K_DIM;
        float a = 0.f;
        #pragma unroll 8
        for (int c = 0; c < NCHUNK_CS; c++) a += sp[(size_t)c * K_DIM + t];
        s_n[t] = a * (1.f / 16.f);
    } else {
        const float* sp = ws + WS_SP + (size_t)b * NCHUNK * 2048 + n * K_DIM;
        float a = 0.f;
        #pragma unroll 8
        for (int c = 0; c < NCHUNK; c++) a += sp[(size_t)c * 2048 + t];
        s_n[t] = a;
    }
    __syncthreads();

    {
        const int d = t >> 3, kseg = t & 7;
        const int col = n * 16 + d;
        float p = 0.f;
        #pragma unroll
        for (int j = 0; j < 16; j++) {
            int k = kseg * 16 + j;
            p += s_n[k] * W[k * 256 + col];
        }
        p += __shfl_xor(p, 1); p += __shfl_xor(p, 2); p += __shfl_xor(p, 4);
        if (kseg == 0) o_s[d] = p;
    }
    __syncthreads();

    float ss = (mode == 2) ? 1e-7f : 0.f;
    #pragma unroll
    for (int d = 0; d < 16; d++) { float v = o_s[d]; ss += v * v; }

    if (mode == 2) {
        if (t < 16) {
            float scale = sqrtf(ss) / (0.5f + ss);
            out[b * 256 + n * 16 + t] = scale * o_s[t];
        }
        return;
    }

    const float inv = rsqrtf(fmaxf(ss, 1e-12f));
    const float4* wrow = (const float4*)(W + t * 256 + n * 16);
    const float4* o4 = (const float4*)o_s;
    float acc = 0.f;
    #pragma unroll
    for (int q = 0; q < 4; q++) {
        float4 w = wrow[q];
        float4 o = o4[q];
        acc += w.x * o.x + w.y * o.y + w.z * o.z + w.w * o.w;
    }
    ws[WS_WO + (size_t)b * 2048 + n * K_DIM + t] = acc * inv;
}

// ---------------------------------------------------------------------------
// K3a: MFMA routing pass, both phases on matrix cores.
// grid (32, B), block 256 (4 waves). Phase 1: logits D[i][cap] = u . wo^T.
// Phase 2: s D[k][cap] = u^T . c  (A = u_t frags, B = c frags).
__global__ __launch_bounds__(256) void routing_mfma(float* __restrict__ ws) {
    const int b = blockIdx.y, chunk = blockIdx.x, t = threadIdx.x;
    const int lane = t & 63, wave = t >> 6;
    const short* up = (const short*)(ws + WS_PACK);
    const short* utp = (const short*)(ws + WS_PACKT);

    __shared__ __align__(16) short wo_bf[N_CAP][144];
    __shared__ float c_s[RCHUNK][18];   // pad 18: spreads phase-2 B-frag reads

    const float* wo = ws + WS_WO + (size_t)b * 2048;
    #pragma unroll
    for (int j = 0; j < 8; j++) {
        int idx = t + j * 256;
        wo_bf[idx >> 7][idx & 127] = (short)f2bf(wo[idx]);
    }
    __syncthreads();

    const int cap = lane & 15, hi = lane >> 4;
    bf16x8 bfrag[4];
    #pragma unroll
    for (int kt = 0; kt < 4; kt++)
        bfrag[kt] = *(const bf16x8*)&wo_bf[cap][kt * 32 + hi * 8];

    // ---- phase 1: logits + softmax -> c_s ----
    #pragma unroll
    for (int rr = 0; rr < 2; rr++) {
        const int rt = wave * 2 + rr;
        const int rt_g = chunk * 8 + rt;
        f32x4 acc = {0.f, 0.f, 0.f, 0.f};
        const short* abase = up + (((size_t)(b * 256 + rt_g)) * 4) * 512 + lane * 8;
        #pragma unroll
        for (int kt = 0; kt < 4; kt++) {
            bf16x8 a = *(const bf16x8*)(abase + kt * 512);
            acc = __builtin_amdgcn_mfma_f32_16x16x32_bf16(a, bfrag[kt], acc, 0, 0, 0);
        }
        #pragma unroll
        for (int r = 0; r < 4; r++) {
            float v = acc[r];
            float mx = v;
            mx = fmaxf(mx, __shfl_xor(mx, 1)); mx = fmaxf(mx, __shfl_xor(mx, 2));
            mx = fmaxf(mx, __shfl_xor(mx, 4)); mx = fmaxf(mx, __shfl_xor(mx, 8));
            float e = __expf(v - mx);
            float sm = e;
            sm += __shfl_xor(sm, 1); sm += __shfl_xor(sm, 2);
            sm += __shfl_xor(sm, 4); sm += __shfl_xor(sm, 8);
            c_s[rt * 16 + hi * 4 + r][cap] = e / sm;
        }
    }
    __syncthreads();

    // ---- phase 2: s[k][cap] via MFMA. Wave handles ktiles {2w, 2w+1}. ----
    f32x4 s0 = {0.f, 0.f, 0.f, 0.f}, s1 = {0.f, 0.f, 0.f, 0.f};
    const size_t ut_b = ((size_t)b * 8) * 128;   // tile units
    #pragma unroll
    for (int ic = 0; ic < 4; ic++) {
        // B-frag: lane holds c[ic*32 + hi*8 + j][cap], j=0..7
        bf16x8 bfr;
        #pragma unroll
        for (int j = 0; j < 8; j++)
            bfr[j] = (short)f2bf(c_s[ic * 32 + hi * 8 + j][cap]);
        const short* ab0 = utp + (((ut_b + (size_t)(wave * 2 + 0) * 128) + chunk * 4 + ic) * 64 + lane) * 8;
        const short* ab1 = utp + (((ut_b + (size_t)(wave * 2 + 1) * 128) + chunk * 4 + ic) * 64 + lane) * 8;
        bf16x8 a0 = *(const bf16x8*)ab0;
        bf16x8 a1 = *(const bf16x8*)ab1;
        s0 = __builtin_amdgcn_mfma_f32_16x16x32_bf16(a0, bfr, s0, 0, 0, 0);
        s1 = __builtin_amdgcn_mfma_f32_16x16x32_bf16(a1, bfr, s1, 0, 0, 0);
    }
    // D layout: col=lane&15=cap, row=(lane>>4)*4+r = k_local
    float* sp = ws + WS_SP + ((size_t)b * NCHUNK + chunk) * 2048;
    #pragma unroll
    for (int r = 0; r < 4; r++) {
        sp[cap * K_DIM + (wave * 2 + 0) * 16 + hi * 4 + r] = s0[r];
        sp[cap * K_DIM + (wave * 2 + 1) * 16 + hi * 4 + r] = s1[r];
    }
}

// ---------------------------------------------------------------------------
// K3b: fp32 fallback routing if ws too small for the packed buffers.
__global__ __launch_bounds__(256) void routing_fp32(const float* __restrict__ u,
                                                    float* __restrict__ ws) {
    const int b = blockIdx.y, chunk = blockIdx.x, t = threadIdx.x;
    const int i0 = chunk * RCHUNK;

    __shared__ __align__(16) float wo_s[N_CAP][K_DIM];
    __shared__ __align__(16) float c_s[RCHUNK][N_CAP];

    const float* w_o = ws + WS_WO + (size_t)b * 2048;
    #pragma unroll
    for (int j = 0; j < 8; j++) {
        int idx = t + j * 256;
        ((float*)wo_s)[idx] = w_o[idx];
    }
    __syncthreads();

    {
        const int row = t >> 1, h = t & 1;
        const float4* upx = (const float4*)(u + ((size_t)b * I_TOT + i0 + row) * K_DIM + h * 64);
        const float4* wp = (const float4*)&wo_s[0][h * 64];
        float logit[16];
        #pragma unroll
        for (int n = 0; n < 16; n++) logit[n] = 0.f;
        #pragma unroll
        for (int q = 0; q < 16; q++) {
            float4 v = upx[q];
            #pragma unroll
            for (int n = 0; n < 16; n++) {
                float4 w = wp[n * 32 + q];
                logit[n] += v.x * w.x + v.y * w.y + v.z * w.z + v.w * w.w;
            }
        }
        #pragma unroll
        for (int n = 0; n < 16; n++) logit[n] += __shfl_xor(logit[n], 1);
        float m = logit[0];
        #pragma unroll
        for (int n = 1; n < 16; n++) m = fmaxf(m, logit[n]);
        float sum = 0.f;
        #pragma unroll
        for (int n = 0; n < 16; n++) { logit[n] = __expf(logit[n] - m); sum += logit[n]; }
        float inv = 1.f / sum;
        float4* crow = (float4*)&c_s[row][h * 8];
        if (h == 0) {
            crow[0] = make_float4(logit[0]*inv, logit[1]*inv, logit[2]*inv, logit[3]*inv);
            crow[1] = make_float4(logit[4]*inv, logit[5]*inv, logit[6]*inv, logit[7]*inv);
        } else {
            crow[0] = make_float4(logit[8]*inv, logit[9]*inv, logit[10]*inv, logit[11]*inv);
            crow[1] = make_float4(logit[12]*inv, logit[13]*inv, logit[14]*inv, logit[15]*inv);
        }
    }
    __syncthreads();

    const int k4 = t & 31, ng = t >> 5;
    float4 a0 = {0.f,0.f,0.f,0.f}, a1 = {0.f,0.f,0.f,0.f};
    const float4* u2 = (const float4*)(u + ((size_t)b * I_TOT + i0) * K_DIM) + k4;
    #pragma unroll 8
    for (int i = 0; i < RCHUNK; i++) {
        float4 v = u2[(size_t)i * 32];
        float2 c2 = *(const float2*)&c_s[i][ng * 2];
        a0.x += v.x * c2.x; a0.y += v.y * c2.x; a0.z += v.z * c2.x; a0.w += v.w * c2.x;
        a1.x += v.x * c2.y; a1.y += v.y * c2.y; a1.z += v.z * c2.y; a1.w += v.w * c2.y;
    }
    float* sp = ws + WS_SP + ((size_t)b * NCHUNK + chunk) * 2048;
    *(float4*)&sp[(ng * 2 + 0) * K_DIM + k4 * 4] = a0;
    *(float4*)&sp[(ng * 2 + 1) * K_DIM + k4 * 4] = a1;
}

// ---------------------------------------------------------------------------
extern "C" void kernel_launch(void* const* d_in, const int* in_sizes, int n_in,
                              void* d_out, int out_size, void* d_ws, size_t ws_size,
                              hipStream_t stream) {
    const float* u = (const float*)d_in[0];   // (32, 4096, 128) f32
    const float* W = (const float*)d_in[1];   // (128, 256) f32
    float* out = (float*)d_out;               // (32, 16, 16) f32
    float* ws = (float*)d_ws;

    const int big = (ws_size >= (size_t)WS_TOTAL_F * 4) ? 1 : 0;

    pack_kernel<<<dim3(I_TOT / CCHUNK, BATCH), 256, 0, stream>>>(u, ws, big);
    update_kernel<<<dim3(N_CAP, BATCH), 128, 0, stream>>>(W, ws, out, 0);

    for (int pass = 0; pass < 3; pass++) {
        if (big) routing_mfma<<<dim3(NCHUNK, BATCH), 256, 0, stream>>>(ws);
        else     routing_fp32<<<dim3(NCHUNK, BATCH), 256, 0, stream>>>(u, ws);
        update_kernel<<<dim3(N_CAP, BATCH), 128, 0, stream>>>(W, ws, out, pass == 2 ? 2 : 1);
    }
}